// Round 1
// baseline (31.384 us; speedup 1.0000x reference)
//
#include <hip/hip_runtime.h>

#define KS   7
#define RAD  3
#define TS   16
#define HT   22        // TS + 2*RAD
#define PITCH 23       // padded tile row length in float4 units (odd -> breaks bank alias)
#define H    256
#define W    256
#define C    32
#define BATCH 2

__global__ __launch_bounds__(256)
void bilateral_kernel(const float* __restrict__ in,      // [B][32][H][W]
                      const float* __restrict__ guide,   // [B][3][H][W]
                      const float* __restrict__ sigma_p, // [1]
                      float* __restrict__ out) {         // [B][32][H][W]
    __shared__ float4 gtile[HT][PITCH];
    __shared__ float4 itile[HT][PITCH];

    const int tx = threadIdx.x & 15;
    const int ty = threadIdx.x >> 4;
    const int x0 = blockIdx.x * TS;
    const int y0 = blockIdx.y * TS;
    const int b  = blockIdx.z;

    // spatial factors (normalization of g2 cancels in ker/norm)
    const float sigma = sigma_p[0];
    const float inv2s2 = 0.5f / (sigma * sigma);
    float e[KS];
#pragma unroll
    for (int i = 0; i < KS; ++i) {
        float r = (float)(i - RAD);
        e[i] = __expf(-r * r * inv2s2);
    }

    // ---- stage guide tile (3 channels packed in float4, zero-filled halo) ----
    const float* gb = guide + (size_t)b * 3 * H * W;
    for (int idx = threadIdx.x; idx < HT * HT; idx += 256) {
        int row = idx / HT;
        int col = idx - row * HT;
        int gy = y0 - RAD + row;
        int gx = x0 - RAD + col;
        float4 v = make_float4(0.f, 0.f, 0.f, 0.f);
        if (gy >= 0 && gy < H && gx >= 0 && gx < W) {
            int off = gy * W + gx;
            v.x = gb[off];
            v.y = gb[H * W + off];
            v.z = gb[2 * H * W + off];
        }
        gtile[row][col] = v;
    }
    __syncthreads();

    // ---- per-pixel raw (unnormalized) bilateral weights, kept in registers ----
    float wk[KS * KS];
    float norm = 0.f;
    const float4 gc = gtile[ty + RAD][tx + RAD];
#pragma unroll
    for (int di = 0; di < KS; ++di) {
#pragma unroll
        for (int dj = 0; dj < KS; ++dj) {
            float4 gv = gtile[ty + di][tx + dj];
            float dx = gv.x - gc.x;
            float dy = gv.y - gc.y;
            float dz = gv.z - gc.z;
            float s = dx * dx + dy * dy + dz * dz;
            float wgt = e[di] * e[dj] * __expf(-0.5f * s);
            wk[di * KS + dj] = wgt;
            norm += wgt;
        }
    }
    const float inv = 1.f / norm;   // norm >= center weight = 1, never 0

    const float* inb  = in  + (size_t)b * C * H * W;
    float*       outb = out + (size_t)b * C * H * W;
    const int y = y0 + ty;
    const int x = x0 + tx;

    // ---- apply: 8 groups of 4 channels packed as float4 in LDS ----
    for (int cg = 0; cg < C; cg += 4) {
        __syncthreads();   // previous itile reads done before overwrite
        const float* cbase = inb + (size_t)cg * H * W;
        for (int idx = threadIdx.x; idx < HT * HT; idx += 256) {
            int row = idx / HT;
            int col = idx - row * HT;
            int gy = y0 - RAD + row;
            int gx = x0 - RAD + col;
            float4 v = make_float4(0.f, 0.f, 0.f, 0.f);
            if (gy >= 0 && gy < H && gx >= 0 && gx < W) {
                const float* p = cbase + gy * W + gx;
                v.x = p[0];
                v.y = p[H * W];
                v.z = p[2 * H * W];
                v.w = p[3 * H * W];
            }
            itile[row][col] = v;
        }
        __syncthreads();

        float4 acc = make_float4(0.f, 0.f, 0.f, 0.f);
#pragma unroll
        for (int di = 0; di < KS; ++di) {
#pragma unroll
            for (int dj = 0; dj < KS; ++dj) {
                float4 iv = itile[ty + di][tx + dj];
                float wgt = wk[di * KS + dj];
                acc.x += wgt * iv.x;
                acc.y += wgt * iv.y;
                acc.z += wgt * iv.z;
                acc.w += wgt * iv.w;
            }
        }
        float* po = outb + (size_t)cg * H * W + y * W + x;
        po[0]         = acc.x * inv;
        po[H * W]     = acc.y * inv;
        po[2 * H * W] = acc.z * inv;
        po[3 * H * W] = acc.w * inv;
    }
}

extern "C" void kernel_launch(void* const* d_in, const int* in_sizes, int n_in,
                              void* d_out, int out_size, void* d_ws, size_t ws_size,
                              hipStream_t stream) {
    const float* in    = (const float*)d_in[0];
    const float* guide = (const float*)d_in[1];
    const float* sigma = (const float*)d_in[2];
    float* out = (float*)d_out;
    dim3 grid(W / TS, H / TS, BATCH);
    bilateral_kernel<<<grid, dim3(256), 0, stream>>>(in, guide, sigma, out);
}

// Round 2
// 28.084 us; speedup vs baseline: 1.1175x; 1.1175x over previous
//
#include <hip/hip_runtime.h>

#define KS    7
#define RAD   3
#define TW    32          // tile width (output px)
#define TH    16          // tile height
#define HCOLS 38          // TW + 2*RAD (halo cols, float4 units)
#define HROWS 22          // TH + 2*RAD
#define PITCH 43          // skewed physical row length: max swz(37)=41, +pad
#define NTILE (HROWS*HCOLS)   // 836
#define H     256
#define W     256
#define HWp   (H*W)
#define NSTAGE 4          // ceil(836/256)

// skew: spreads stride-2 float4 reads across all 8 4-bank groups
__device__ __forceinline__ int swz(int c) { return c + (c >> 3); }

__global__ __launch_bounds__(256, 2)
void bilateral_kernel(const float* __restrict__ in,      // [B][32][H][W]
                      const float* __restrict__ guide,   // [B][3][H][W]
                      const float* __restrict__ sigma_p, // [1]
                      float* __restrict__ out)           // [B][32][H][W]
{
    __shared__ float4 gtile[HROWS * PITCH];
    __shared__ float4 itile[2][HROWS * PITCH];

    const int tid = threadIdx.x;
    const int tx  = tid & 15;
    const int ty  = tid >> 4;
    const int x0  = blockIdx.x * TW;
    const int y0  = blockIdx.y * TH;
    const int b   = blockIdx.z;

    const float* gb   = guide + (size_t)b * 3  * HWp;
    const float* inb  = in    + (size_t)b * 32 * HWp;
    float*       outb = out   + (size_t)b * 32 * HWp;

    const float sigma  = sigma_p[0];
    const float inv2s2 = 0.5f / (sigma * sigma);
    float e[KS];
#pragma unroll
    for (int i = 0; i < KS; ++i) {
        float r = (float)(i - RAD);
        e[i] = __expf(-r * r * inv2s2);
    }

    // ---- stage guide tile (3 ch packed in float4, zero halo, skewed) ----
#pragma unroll
    for (int it = 0; it < NSTAGE; ++it) {
        int idx = tid + it * 256;
        if (idx < NTILE) {
            int row = idx / HCOLS;
            int col = idx - row * HCOLS;
            int gy = y0 - RAD + row, gx = x0 - RAD + col;
            float4 v = make_float4(0.f, 0.f, 0.f, 0.f);
            if (gy >= 0 && gy < H && gx >= 0 && gx < W) {
                const float* p = gb + gy * W + gx;
                v.x = p[0]; v.y = p[HWp]; v.z = p[2 * HWp];
            }
            gtile[row * PITCH + swz(col)] = v;
        }
    }

    float4 pre[NSTAGE];

#define GATHER(cgrp) do {                                                    \
        const float* cb_ = inb + (size_t)((cgrp) * 4) * HWp;                 \
        _Pragma("unroll")                                                    \
        for (int it = 0; it < NSTAGE; ++it) {                                \
            int idx = tid + it * 256;                                        \
            float4 v = make_float4(0.f, 0.f, 0.f, 0.f);                      \
            if (idx < NTILE) {                                               \
                int row = idx / HCOLS;                                       \
                int col = idx - row * HCOLS;                                 \
                int gy = y0 - RAD + row, gx = x0 - RAD + col;                \
                if (gy >= 0 && gy < H && gx >= 0 && gx < W) {                \
                    const float* p_ = cb_ + gy * W + gx;                     \
                    v.x = p_[0];       v.y = p_[HWp];                        \
                    v.z = p_[2 * HWp]; v.w = p_[3 * HWp];                    \
                }                                                            \
            }                                                                \
            pre[it] = v;                                                     \
        } } while (0)

#define WRITEPRE(dst) do {                                                   \
        _Pragma("unroll")                                                    \
        for (int it = 0; it < NSTAGE; ++it) {                                \
            int idx = tid + it * 256;                                        \
            if (idx < NTILE) {                                               \
                int row = idx / HCOLS;                                       \
                int col = idx - row * HCOLS;                                 \
                (dst)[row * PITCH + swz(col)] = pre[it];                     \
            }                                                                \
        } } while (0)

    GATHER(0);                 // cg0 loads fly during guide-tile barrier
    __syncthreads();           // gtile ready

    WRITEPRE(itile[0]);        // drain cg0 into buffer 0
    GATHER(1);                 // cg1 loads fly during weight compute

    // ---- per-pixel unnormalized weights for BOTH pixels, in registers ----
    float wk0[KS * KS], wk1[KS * KS];
    float norm0 = 0.f, norm1 = 0.f;
    const float4 gc0 = gtile[(ty + RAD) * PITCH + swz(2 * tx + RAD)];
    const float4 gc1 = gtile[(ty + RAD) * PITCH + swz(2 * tx + RAD + 1)];
#pragma unroll
    for (int di = 0; di < KS; ++di) {
        float4 r[8];
#pragma unroll
        for (int k = 0; k < 8; ++k)
            r[k] = gtile[(ty + di) * PITCH + swz(2 * tx + k)];
#pragma unroll
        for (int dj = 0; dj < KS; ++dj) {
            float ee = e[di] * e[dj];
            float dx = r[dj].x - gc0.x, dy = r[dj].y - gc0.y, dz = r[dj].z - gc0.z;
            float w0 = ee * __expf(-0.5f * (dx * dx + dy * dy + dz * dz));
            wk0[di * KS + dj] = w0;  norm0 += w0;
            dx = r[dj + 1].x - gc1.x; dy = r[dj + 1].y - gc1.y; dz = r[dj + 1].z - gc1.z;
            float w1 = ee * __expf(-0.5f * (dx * dx + dy * dy + dz * dz));
            wk1[di * KS + dj] = w1;  norm1 += w1;
        }
    }
    const float inv0 = 1.f / norm0;   // norm >= center weight = 1
    const float inv1 = 1.f / norm1;

    __syncthreads();           // itile[0] ready

    const int y = y0 + ty;
    const int x = x0 + 2 * tx;

    for (int cg = 0; cg < 8; ++cg) {
        const float4* rbuf = itile[cg & 1];
        if (cg < 7) {
            WRITEPRE(itile[(cg + 1) & 1]);   // buffer last read 2 iters ago
            if (cg < 6) GATHER(cg + 2);      // loads hide under compute
        }
        float4 a0 = make_float4(0.f, 0.f, 0.f, 0.f);
        float4 a1 = make_float4(0.f, 0.f, 0.f, 0.f);
#pragma unroll
        for (int di = 0; di < KS; ++di) {
            float4 r[8];
#pragma unroll
            for (int k = 0; k < 8; ++k)
                r[k] = rbuf[(ty + di) * PITCH + swz(2 * tx + k)];
#pragma unroll
            for (int dj = 0; dj < KS; ++dj) {
                float w0 = wk0[di * KS + dj], w1 = wk1[di * KS + dj];
                a0.x += w0 * r[dj].x;     a0.y += w0 * r[dj].y;
                a0.z += w0 * r[dj].z;     a0.w += w0 * r[dj].w;
                a1.x += w1 * r[dj + 1].x; a1.y += w1 * r[dj + 1].y;
                a1.z += w1 * r[dj + 1].z; a1.w += w1 * r[dj + 1].w;
            }
        }
        size_t o = (size_t)(cg * 4) * HWp + (size_t)y * W + x;
        float2 s;
        s.x = a0.x * inv0; s.y = a1.x * inv1; *(float2*)(outb + o)           = s;
        s.x = a0.y * inv0; s.y = a1.y * inv1; *(float2*)(outb + o + HWp)     = s;
        s.x = a0.z * inv0; s.y = a1.z * inv1; *(float2*)(outb + o + 2 * HWp) = s;
        s.x = a0.w * inv0; s.y = a1.w * inv1; *(float2*)(outb + o + 3 * HWp) = s;
        __syncthreads();   // compute(cg) reads done before buffer reuse
    }
}

extern "C" void kernel_launch(void* const* d_in, const int* in_sizes, int n_in,
                              void* d_out, int out_size, void* d_ws, size_t ws_size,
                              hipStream_t stream) {
    const float* in    = (const float*)d_in[0];
    const float* guide = (const float*)d_in[1];
    const float* sigma = (const float*)d_in[2];
    float* out = (float*)d_out;
    dim3 grid(W / TW, H / TH, 2);
    bilateral_kernel<<<grid, dim3(256), 0, stream>>>(in, guide, sigma, out);
}